// Round 3
// baseline (21351.344 us; speedup 1.0000x reference)
//
#include <hip/hip_runtime.h>
#include <cstdint>

// ---------------------------------------------------------------------------
// SparseAttention — CORRECTNESS-FIRST baseline (no MFMA, no global_load_lds,
// no swizzles, no LDS type-punning). Establish a passing anchor, then
// re-introduce performance machinery incrementally in later rounds.
//
// B=2, N=2048, C=1024, H=16, hd=64, k_sparse=204.
//  - qkv projection in fp64 (textbook tiled VALU GEMM)
//  - scores in fp64 registers; exact rank-204 threshold by 64-step binary
//    search on order-preserving u64 bit patterns (matches np top_k exactly)
//  - softmax / PV / out-projection in fp32 (smooth path; error ~1e-5)
// ---------------------------------------------------------------------------

#define BB 2
#define NN 2048
#define CC 1024
#define HH 16
#define HD 64
#define KSP 204

// ---------------------------------------------------------------------------
// Kernel 1: qkv = x @ w_qkv + b_qkv in fp64.
// x [4096][1024] fp32, w [1024][3072] fp32.
// Outputs: Qd [bh][d][n] fp64 (pre-scaled by 0.125 — exact pow2),
//          Kd [bh][d][n] fp64, Vf [bh][d][n] fp32.
// ---------------------------------------------------------------------------
__global__ __launch_bounds__(256) void qkv_gemm_f64(
    const float* __restrict__ x, const float* __restrict__ w,
    const float* __restrict__ bqkv, double* __restrict__ Qd,
    double* __restrict__ Kd, float* __restrict__ Vf) {
  __shared__ double As[16][17];
  __shared__ double Bs[16][17];
  const int tid = threadIdx.x;
  const int tx = tid & 15, ty = tid >> 4;
  const int col = blockIdx.x * 16 + tx;
  const int row = blockIdx.y * 16 + ty;
  const int colbase = blockIdx.x * 16;
  const int rowbase = blockIdx.y * 16;

  double acc = 0.0;
  for (int kt = 0; kt < 64; ++kt) {
    const int k0 = kt * 16;
    As[ty][tx] = (double)x[(size_t)(rowbase + ty) * 1024 + k0 + tx];
    Bs[ty][tx] = (double)w[(size_t)(k0 + ty) * 3072 + colbase + tx];
    __syncthreads();
#pragma unroll
    for (int k = 0; k < 16; ++k) acc = fma(As[ty][k], Bs[k][tx], acc);
    __syncthreads();
  }

  const double v = acc + (double)bqkv[col];
  const int region = col >> 10;          // 0=Q 1=K 2=V
  const int h = (col & 1023) >> 6;
  const int d = col & 63;
  const int b = row >> 11;
  const int n = row & 2047;
  const size_t o = ((size_t)((b * HH + h) * HD + d)) * NN + n;
  if (region == 0)
    Qd[o] = v * 0.125;                   // exact: power-of-two scale
  else if (region == 1)
    Kd[o] = v;
  else
    Vf[o] = (float)v;
}

// ---------------------------------------------------------------------------
// Kernel 2: fused sparse attention.
// Grid: 32 bh x 256 tiles of 8 q-rows. Block 512 thr = 8 waves.
// Wave r owns q-row n0+r: scores for all 2048 keys in 32 fp64 regs/lane
// (key = lane + 64*i). Exact top-204 threshold via binary search on
// monotone u64 keys. Softmax fp32 -> Pf in LDS. PV: wave w owns d-chunk.
// ---------------------------------------------------------------------------
__global__ __launch_bounds__(512) void attn_exact(
    const double* __restrict__ Qd, const double* __restrict__ Kd,
    const float* __restrict__ Vf, float* __restrict__ attnv) {
  __shared__ double Qrow[8][64];
  __shared__ float Pf[8][2048];
  __shared__ float Zrow[8];

  const int tid = threadIdx.x;
  const int lane = tid & 63;
  const int wv = tid >> 6;               // 0..7: q-row role, then d-chunk role
  const int bh = (int)blockIdx.x >> 8;
  const int n0 = ((int)blockIdx.x & 255) * 8;

  // stage Q rows: thread (wv, lane) loads Qrow[wv][lane]
  Qrow[wv][lane] = Qd[((size_t)bh * HD + lane) * NN + n0 + wv];
  __syncthreads();

  // ---- scores: acc[i] = S[n0+wv][lane + 64*i], fp64 ----
  double acc[32];
#pragma unroll
  for (int i = 0; i < 32; ++i) acc[i] = 0.0;
  {
    const double* Kb = Kd + (size_t)bh * HD * NN + lane;
#pragma unroll 2
    for (int d = 0; d < 64; ++d) {
      const double qv = Qrow[wv][d];
      const double* kr = Kb + (size_t)d * NN;
#pragma unroll
      for (int i = 0; i < 32; ++i) acc[i] = fma(qv, kr[i * 64], acc[i]);
    }
  }

  // ---- row max (fp64) ----
  double mx = acc[0];
#pragma unroll
  for (int i = 1; i < 32; ++i) mx = fmax(mx, acc[i]);
#pragma unroll
  for (int m = 1; m < 64; m <<= 1) mx = fmax(mx, __shfl_xor(mx, m, 64));

  // ---- map to order-preserving u64 (descending rank = descending u) ----
  unsigned long long ua[32];
#pragma unroll
  for (int i = 0; i < 32; ++i) {
    long long bb = __double_as_longlong(acc[i]);
    ua[i] = (unsigned long long)bb ^
            ((bb < 0) ? 0xFFFFFFFFFFFFFFFFull : 0x8000000000000000ull);
  }

  // ---- exact 204th-largest value: binary search on bit prefix ----
  unsigned long long T = 0ull;
#pragma unroll 1
  for (int bit = 63; bit >= 0; --bit) {
    const unsigned long long cand = T | (1ull << bit);
    int c = 0;
#pragma unroll
    for (int i = 0; i < 32; ++i) c += (ua[i] >= cand) ? 1 : 0;
#pragma unroll
    for (int m = 1; m < 64; m <<= 1) c += __shfl_xor(c, m, 64);
    if (c >= KSP) T = cand;
  }

  // ---- softmax numerators (fp32) + Z ----
  float z = 0.f;
#pragma unroll
  for (int i = 0; i < 32; ++i) {
    const float p =
        (ua[i] >= T) ? __expf((float)(acc[i] - mx)) : 0.0f;
    Pf[wv][lane + 64 * i] = p;
    z += p;
  }
#pragma unroll
  for (int m = 1; m < 64; m <<= 1) z += __shfl_xor(z, m, 64);
  if (lane == 0) Zrow[wv] = z;
  __syncthreads();

  // ---- PV: wave wv owns d in [wv*8, wv*8+8) ----
  const int b2 = bh >> 4, h2 = bh & 15;
#pragma unroll 1
  for (int dd = 0; dd < 8; ++dd) {
    const int d = wv * 8 + dd;
    const float* vr = Vf + ((size_t)bh * HD + d) * NN + lane;
    float vv[32];
#pragma unroll
    for (int i = 0; i < 32; ++i) vv[i] = vr[i * 64];
#pragma unroll 1
    for (int r2 = 0; r2 < 8; ++r2) {
      float s = 0.f;
#pragma unroll
      for (int i = 0; i < 32; ++i) s = fmaf(Pf[r2][lane + 64 * i], vv[i], s);
#pragma unroll
      for (int m = 1; m < 64; m <<= 1) s += __shfl_xor(s, m, 64);
      if (lane == 0)
        attnv[((size_t)(b2 * NN + n0 + r2)) * CC + h2 * HD + d] =
            s / Zrow[r2];
    }
  }
}

// ---------------------------------------------------------------------------
// Kernel 3: out = attnv @ w_out + b_out, fp32 textbook tiled GEMM.
// attnv [4096][1024] fp32, w_out [1024][1024] fp32.
// ---------------------------------------------------------------------------
__global__ __launch_bounds__(256) void out_gemm_f32(
    const float* __restrict__ A, const float* __restrict__ W,
    const float* __restrict__ bout, float* __restrict__ out) {
  __shared__ float As[16][17];
  __shared__ float Bs[16][17];
  const int tid = threadIdx.x;
  const int tx = tid & 15, ty = tid >> 4;
  const int col = blockIdx.x * 16 + tx;
  const int row = blockIdx.y * 16 + ty;
  const int colbase = blockIdx.x * 16;
  const int rowbase = blockIdx.y * 16;

  float acc = 0.f;
  for (int kt = 0; kt < 64; ++kt) {
    const int k0 = kt * 16;
    As[ty][tx] = A[(size_t)(rowbase + ty) * 1024 + k0 + tx];
    Bs[ty][tx] = W[(size_t)(k0 + ty) * 1024 + colbase + tx];
    __syncthreads();
#pragma unroll
    for (int k = 0; k < 16; ++k) acc = fmaf(As[ty][k], Bs[k][tx], acc);
    __syncthreads();
  }
  out[(size_t)row * CC + col] = acc + bout[col];
}

// ---------------------------------------------------------------------------
extern "C" void kernel_launch(void* const* d_in, const int* in_sizes, int n_in,
                              void* d_out, int out_size, void* d_ws,
                              size_t ws_size, hipStream_t stream) {
  const float* x     = (const float*)d_in[0];
  const float* w_qkv = (const float*)d_in[1];
  const float* b_qkv = (const float*)d_in[2];
  const float* w_out = (const float*)d_in[3];
  const float* b_out = (const float*)d_in[4];
  float* out = (float*)d_out;

  char* ws = (char*)d_ws;
  const size_t SZ_QD = (size_t)BB * HH * HD * NN * 8;  // 33.55 MB
  const size_t SZ_VF = (size_t)BB * HH * HD * NN * 4;  // 16.78 MB
  const size_t SZ_AT = (size_t)4096 * 1024 * 4;        // 16.78 MB

  size_t off = 0;
  double* Qd    = (double*)(ws + off); off += SZ_QD;
  double* Kd    = (double*)(ws + off); off += SZ_QD;
  float*  Vf    = (float*)(ws + off);  off += SZ_VF;
  float*  attnv = (float*)(ws + off);  off += SZ_AT;

  {
    dim3 g(3072 / 16, 4096 / 16);
    qkv_gemm_f64<<<g, 256, 0, stream>>>(x, w_qkv, b_qkv, Qd, Kd, Vf);
  }
  attn_exact<<<BB * HH * (NN / 8), 512, 0, stream>>>(Qd, Kd, Vf, attnv);
  {
    dim3 g(1024 / 16, 4096 / 16);
    out_gemm_f32<<<g, 256, 0, stream>>>(attnv, w_out, b_out, out);
  }
}

// Round 4
// 4199.232 us; speedup vs baseline: 5.0846x; 5.0846x over previous
//
#include <hip/hip_runtime.h>
#include <cstdint>

// ---------------------------------------------------------------------------
// SparseAttention — R4: same verified semantics as the R3 anchor, with the
// latency/spill pathologies fixed.
//  - attn scores: K staged through LDS (2 d-rows x 2048 keys fp64 per stage),
//    identical fp64 summation order to R3 -> bit-identical scores.
//  - rank-204: u32 (monotone fp32-cast) binary search + exact-tie fallback
//    that recomputes fp64 keys on the fly (no ua[32] registers -> no spill).
//    Provably selects the same set as R3's 64-bit search.
//  - Pf f16 (fits LDS for 2 blocks/CU); PV fp32 accumulate.
//  - qkv (fp64) and out-proj (fp32) GEMMs: 64x64 tile, 4x4 micro-tile.
// ---------------------------------------------------------------------------

#define BB 2
#define NN 2048
#define CC 1024
#define HH 16
#define HD 64
#define KSP 204

__device__ __forceinline__ unsigned long long mono64(double s) {
  long long bb = __double_as_longlong(s);
  return (unsigned long long)bb ^
         ((bb < 0) ? 0xFFFFFFFFFFFFFFFFull : 0x8000000000000000ull);
}

// ---------------------------------------------------------------------------
// Kernel 1: qkv = x @ w_qkv + b_qkv in fp64. 64x64 tile, 4x4 micro.
// Outputs: Qd [bh][d][n] fp64 (pre-scaled 0.125), Kd fp64, Vf fp32.
// ---------------------------------------------------------------------------
__global__ __launch_bounds__(256) void qkv_gemm_f64(
    const float* __restrict__ x, const float* __restrict__ w,
    const float* __restrict__ bqkv, double* __restrict__ Qd,
    double* __restrict__ Kd, float* __restrict__ Vf) {
  __shared__ double As[16][64];  // [k][m]
  __shared__ double Bs[16][64];  // [k][n]
  const int tid = threadIdx.x;
  const int tx = tid & 15, ty = tid >> 4;
  const int colbase = blockIdx.x * 64, rowbase = blockIdx.y * 64;

  double acc[4][4] = {};  // row = rowbase+ty+16i, col = colbase+tx+16j

  const int sr = tid >> 2, sc = (tid & 3) * 4;   // A-stage role
  const int bk = tid >> 4, bn = (tid & 15) * 4;  // B-stage role

  for (int kt = 0; kt < 64; ++kt) {
    const int k0 = kt * 16;
    const float4 av = *(const float4*)(x + (size_t)(rowbase + sr) * 1024 + k0 + sc);
    const float4 bv = *(const float4*)(w + (size_t)(k0 + bk) * 3072 + colbase + bn);
    __syncthreads();
    As[sc + 0][sr] = (double)av.x;
    As[sc + 1][sr] = (double)av.y;
    As[sc + 2][sr] = (double)av.z;
    As[sc + 3][sr] = (double)av.w;
    Bs[bk][bn + 0] = (double)bv.x;
    Bs[bk][bn + 1] = (double)bv.y;
    Bs[bk][bn + 2] = (double)bv.z;
    Bs[bk][bn + 3] = (double)bv.w;
    __syncthreads();
#pragma unroll
    for (int k = 0; k < 16; ++k) {
      double a[4], b[4];
#pragma unroll
      for (int i = 0; i < 4; ++i) a[i] = As[k][ty + 16 * i];
#pragma unroll
      for (int j = 0; j < 4; ++j) b[j] = Bs[k][tx + 16 * j];
#pragma unroll
      for (int i = 0; i < 4; ++i)
#pragma unroll
        for (int j = 0; j < 4; ++j) acc[i][j] = fma(a[i], b[j], acc[i][j]);
    }
  }

  const int region = colbase >> 10;  // uniform per block: 0=Q 1=K 2=V
#pragma unroll
  for (int j = 0; j < 4; ++j) {
    const int col = colbase + tx + 16 * j;
    const double bias = (double)bqkv[col];
    const int h = (col & 1023) >> 6, d = col & 63;
#pragma unroll
    for (int i = 0; i < 4; ++i) {
      const int row = rowbase + ty + 16 * i;
      const int b = row >> 11, n = row & 2047;
      const size_t o = ((size_t)((b * HH + h) * HD + d)) * NN + n;
      const double v = acc[i][j] + bias;
      if (region == 0)
        Qd[o] = v * 0.125;
      else if (region == 1)
        Kd[o] = v;
      else
        Vf[o] = (float)v;
    }
  }
}

// ---------------------------------------------------------------------------
// Kernel 2: fused sparse attention (semantics identical to R3 anchor).
// Block 512 thr = 8 waves; wave wv owns q-row n0+wv; lane's keys = lane+64*i.
// ---------------------------------------------------------------------------
__global__ __launch_bounds__(512) void attn_exact(
    const double* __restrict__ Qd, const double* __restrict__ Kd,
    const float* __restrict__ Vf, float* __restrict__ attnv) {
  __shared__ double Qrow[8][64];
  __shared__ double Ks[2][2048];
  __shared__ _Float16 Pf[8][2048];
  __shared__ float Zrow[8];

  const int tid = threadIdx.x;
  const int lane = tid & 63;
  const int wv = tid >> 6;
  const int bh = (int)blockIdx.x >> 8;
  const int n0 = ((int)blockIdx.x & 255) * 8;

  Qrow[wv][lane] = Qd[((size_t)bh * HD + lane) * NN + n0 + wv];

  // ---- scores: acc[i] = S[n0+wv][lane + 64*i], fp64, d-ascending order ----
  double acc[32];
#pragma unroll
  for (int i = 0; i < 32; ++i) acc[i] = 0.0;

  const double* Kbh = Kd + (size_t)bh * HD * NN;
  const int dr = tid >> 8;           // 0..1: which of 2 staged d-rows
  const int kc = (tid & 255) * 8;    // 8-double chunk within the key row
#pragma unroll 1
  for (int dsx = 0; dsx < 32; ++dsx) {
    const double* src = Kbh + (size_t)(dsx * 2 + dr) * NN + kc;
    const double2 v0 = *(const double2*)(src + 0);
    const double2 v1 = *(const double2*)(src + 2);
    const double2 v2 = *(const double2*)(src + 4);
    const double2 v3 = *(const double2*)(src + 6);
    __syncthreads();  // previous stage fully consumed
    *(double2*)&Ks[dr][kc + 0] = v0;
    *(double2*)&Ks[dr][kc + 2] = v1;
    *(double2*)&Ks[dr][kc + 4] = v2;
    *(double2*)&Ks[dr][kc + 6] = v3;
    __syncthreads();  // stage visible
    const double q0 = Qrow[wv][dsx * 2 + 0];
    const double q1 = Qrow[wv][dsx * 2 + 1];
#pragma unroll
    for (int t = 0; t < 32; ++t) {
      acc[t] = fma(q0, Ks[0][lane + 64 * t], acc[t]);
      acc[t] = fma(q1, Ks[1][lane + 64 * t], acc[t]);
    }
  }

  // ---- row max (fp64) ----
  double mxd = acc[0];
#pragma unroll
  for (int i = 1; i < 32; ++i) mxd = fmax(mxd, acc[i]);
#pragma unroll
  for (int m = 1; m < 64; m <<= 1) mxd = fmax(mxd, __shfl_xor(mxd, m, 64));

  // ---- monotone u32 keys from fp32 casts ----
  unsigned ka[32];
#pragma unroll
  for (int i = 0; i < 32; ++i) {
    const int ib = __float_as_int((float)acc[i]);
    ka[i] = (unsigned)ib ^ ((ib < 0) ? 0xFFFFFFFFu : 0x80000000u);
  }

  // ---- binary search: largest T32 with count(ka >= T32) >= 204 ----
  unsigned T32 = 0;
#pragma unroll 1
  for (int bit = 31; bit >= 0; --bit) {
    const unsigned cand = T32 | (1u << bit);
    int c = 0;
#pragma unroll
    for (int i = 0; i < 32; ++i) c += (ka[i] >= cand) ? 1 : 0;
#pragma unroll
    for (int m = 1; m < 64; m <<= 1) c += __shfl_xor(c, m, 64);
    if (c >= KSP) T32 = cand;
  }

  // ---- exact-tie accounting ----
  int cpk = 0;
#pragma unroll
  for (int i = 0; i < 32; ++i)
    cpk += (ka[i] > T32) ? (1 << 12) : ((ka[i] == T32) ? 1 : 0);
#pragma unroll
  for (int m = 1; m < 64; m <<= 1) cpk += __shfl_xor(cpk, m, 64);
  const int cgt = cpk >> 12, ceq = cpk & 0xFFF;

  unsigned selmask = 0;
  if (cgt + ceq == KSP) {  // common: fp32-level selection is exact
#pragma unroll
    for (int i = 0; i < 32; ++i)
      selmask |= (ka[i] >= T32) ? (1u << i) : 0u;
  } else {  // rare: resolve ties with exact fp64 keys (recomputed on the fly)
    unsigned long long T = 0ull;
#pragma unroll 1
    for (int bit = 63; bit >= 0; --bit) {
      const unsigned long long cand = T | (1ull << bit);
      int c = 0;
#pragma unroll
      for (int i = 0; i < 32; ++i)
        c += (ka[i] == T32 && mono64(acc[i]) >= cand) ? 1 : 0;
#pragma unroll
      for (int m = 1; m < 64; m <<= 1) c += __shfl_xor(c, m, 64);
      if (cgt + c >= KSP) T = cand;
    }
#pragma unroll
    for (int i = 0; i < 32; ++i)
      selmask |=
          ((ka[i] > T32) || (ka[i] == T32 && mono64(acc[i]) >= T)) ? (1u << i)
                                                                   : 0u;
  }

  // ---- softmax numerators (f16 in LDS) + Z ----
  float z = 0.f;
#pragma unroll
  for (int i = 0; i < 32; ++i) {
    const float p =
        ((selmask >> i) & 1u) ? __expf((float)(acc[i] - mxd)) : 0.0f;
    Pf[wv][lane + 64 * i] = (_Float16)p;
    z += p;
  }
#pragma unroll
  for (int m = 1; m < 64; m <<= 1) z += __shfl_xor(z, m, 64);
  if (lane == 0) Zrow[wv] = z;
  __syncthreads();

  // ---- PV: wave wv owns d in [wv*8, wv*8+8) ----
  const int b2 = bh >> 4, h2 = bh & 15;
#pragma unroll 1
  for (int dd = 0; dd < 8; ++dd) {
    const int d = wv * 8 + dd;
    const float* vr = Vf + ((size_t)bh * HD + d) * NN + lane;
    float vv[32];
#pragma unroll
    for (int i = 0; i < 32; ++i) vv[i] = vr[i * 64];
#pragma unroll 1
    for (int r2 = 0; r2 < 8; ++r2) {
      float s = 0.f;
#pragma unroll
      for (int i = 0; i < 32; ++i)
        s = fmaf((float)Pf[r2][lane + 64 * i], vv[i], s);
#pragma unroll
      for (int m = 1; m < 64; m <<= 1) s += __shfl_xor(s, m, 64);
      if (lane == 0)
        attnv[((size_t)(b2 * NN + n0 + r2)) * CC + h2 * HD + d] = s / Zrow[r2];
    }
  }
}

// ---------------------------------------------------------------------------
// Kernel 3: out = attnv @ w_out + b_out, fp32, 64x64 tile, 4x4 micro.
// ---------------------------------------------------------------------------
__global__ __launch_bounds__(256) void out_gemm_f32(
    const float* __restrict__ A, const float* __restrict__ W,
    const float* __restrict__ bout, float* __restrict__ out) {
  __shared__ float As[16][64];
  __shared__ float Bs[16][64];
  const int tid = threadIdx.x;
  const int tx = tid & 15, ty = tid >> 4;
  const int colbase = blockIdx.x * 64, rowbase = blockIdx.y * 64;

  float acc[4][4] = {};

  const int sr = tid >> 2, sc = (tid & 3) * 4;
  const int bk = tid >> 4, bn = (tid & 15) * 4;

  for (int kt = 0; kt < 64; ++kt) {
    const int k0 = kt * 16;
    const float4 av = *(const float4*)(A + (size_t)(rowbase + sr) * 1024 + k0 + sc);
    const float4 bv = *(const float4*)(W + (size_t)(k0 + bk) * 1024 + colbase + bn);
    __syncthreads();
    As[sc + 0][sr] = av.x;
    As[sc + 1][sr] = av.y;
    As[sc + 2][sr] = av.z;
    As[sc + 3][sr] = av.w;
    Bs[bk][bn + 0] = bv.x;
    Bs[bk][bn + 1] = bv.y;
    Bs[bk][bn + 2] = bv.z;
    Bs[bk][bn + 3] = bv.w;
    __syncthreads();
#pragma unroll
    for (int k = 0; k < 16; ++k) {
      float a[4], b[4];
#pragma unroll
      for (int i = 0; i < 4; ++i) a[i] = As[k][ty + 16 * i];
#pragma unroll
      for (int j = 0; j < 4; ++j) b[j] = Bs[k][tx + 16 * j];
#pragma unroll
      for (int i = 0; i < 4; ++i)
#pragma unroll
        for (int j = 0; j < 4; ++j) acc[i][j] = fmaf(a[i], b[j], acc[i][j]);
    }
  }

#pragma unroll
  for (int j = 0; j < 4; ++j) {
    const int col = colbase + tx + 16 * j;
    const float bias = bout[col];
#pragma unroll
    for (int i = 0; i < 4; ++i) {
      const int row = rowbase + ty + 16 * i;
      out[(size_t)row * CC + col] = acc[i][j] + bias;
    }
  }
}

// ---------------------------------------------------------------------------
extern "C" void kernel_launch(void* const* d_in, const int* in_sizes, int n_in,
                              void* d_out, int out_size, void* d_ws,
                              size_t ws_size, hipStream_t stream) {
  const float* x     = (const float*)d_in[0];
  const float* w_qkv = (const float*)d_in[1];
  const float* b_qkv = (const float*)d_in[2];
  const float* w_out = (const float*)d_in[3];
  const float* b_out = (const float*)d_in[4];
  float* out = (float*)d_out;

  char* ws = (char*)d_ws;
  const size_t SZ_QD = (size_t)BB * HH * HD * NN * 8;  // 33.55 MB
  const size_t SZ_VF = (size_t)BB * HH * HD * NN * 4;  // 16.78 MB
  const size_t SZ_AT = (size_t)4096 * 1024 * 4;        // 16.78 MB

  size_t off = 0;
  double* Qd    = (double*)(ws + off); off += SZ_QD;
  double* Kd    = (double*)(ws + off); off += SZ_QD;
  float*  Vf    = (float*)(ws + off);  off += SZ_VF;
  float*  attnv = (float*)(ws + off);  off += SZ_AT;

  {
    dim3 g(3072 / 64, 4096 / 64);
    qkv_gemm_f64<<<g, 256, 0, stream>>>(x, w_qkv, b_qkv, Qd, Kd, Vf);
  }
  attn_exact<<<BB * HH * (NN / 8), 512, 0, stream>>>(Qd, Kd, Vf, attnv);
  {
    dim3 g(1024 / 64, 4096 / 64);
    out_gemm_f32<<<g, 256, 0, stream>>>(attnv, w_out, b_out, out);
  }
}